// Round 3
// baseline (912.661 us; speedup 1.0000x reference)
//
#include <hip/hip_runtime.h>
#include <stdint.h>

// 3-layer GCN. Edge-parallel aggregation over dst-bucketed edges with
// per-bucket LDS accumulators (ds_add_f32) -- no CSR, no global float atomics.
// Bucket = 256 consecutive dst nodes. binned[i] = (src<<8)|(dst&255).
// Factorization: layer1 aggregates x (dim2); layer2 aggregates h1 (dim30,
// fused with layer2 math); layer3 aggregates z2@W3 (dim1).

#define NBB 1024  // binning blocks

__global__ void k_detect(const unsigned* ei, int* flag) {
    __shared__ int nz;
    if (threadIdx.x == 0) nz = 0;
    __syncthreads();
    unsigned v = ei[2 * threadIdx.x + 1];
    if (v != 0) atomicAdd(&nz, 1);
    __syncthreads();
    if (threadIdx.x == 0) *flag = (nz == 0) ? 1 : 0;  // all-zero high words => int64
}

// Pass A: per-block bucket histogram -> block_cnt[bucket*NBB + blk]
__global__ void k_binA(const void* ei, long long E, const int* flag,
                       int* block_cnt, int B) {
    extern __shared__ int hist[];
    int t = threadIdx.x, blk = blockIdx.x;
    for (int i = t; i < B; i += 256) hist[i] = 0;
    __syncthreads();
    int f = *flag;
    long long chunk = (E + NBB - 1) / NBB;
    long long s = (long long)blk * chunk, e = min(E, s + chunk);
    if (f) {
        const long long* p = (const long long*)ei;
        for (long long i = s + t; i < e; i += 256)
            atomicAdd(&hist[((int)p[E + i]) >> 8], 1);
    } else {
        const int* p = (const int*)ei;
        for (long long i = s + t; i < e; i += 256)
            atomicAdd(&hist[p[E + i] >> 8], 1);
    }
    __syncthreads();
    for (int i = t; i < B; i += 256) block_cnt[i * NBB + blk] = hist[i];
}

// Per-bucket exclusive scan over the NBB block counts (in place); totals out.
__global__ void k_colsum(int* block_cnt, int* bucket_cnt) {
    __shared__ int sh[256];
    int t = threadIdx.x, b = blockIdx.x;
    int4 c = *(int4*)(block_cnt + (size_t)b * NBB + t * 4);
    int tot = c.x + c.y + c.z + c.w;
    sh[t] = tot;
    __syncthreads();
    for (int off = 1; off < 256; off <<= 1) {
        int add = (t >= off) ? sh[t - off] : 0;
        __syncthreads();
        sh[t] += add;
        __syncthreads();
    }
    int ex = sh[t] - tot;
    int4 o;
    o.x = ex; o.y = ex + c.x; o.z = o.y + c.y; o.w = o.z + c.z;
    *(int4*)(block_cnt + (size_t)b * NBB + t * 4) = o;
    if (t == 255) bucket_cnt[b] = sh[255];
}

// Exclusive scan over buckets -> bucket_base[0..B].
__global__ void k_bucketscan(const int* bucket_cnt, int* bucket_base, int B,
                             long long E) {
    __shared__ int sh[256];
    int t = threadIdx.x;
    int i0 = t * 4;
    int v[4];
    int tot = 0;
    for (int k = 0; k < 4; k++) {
        v[k] = (i0 + k < B) ? bucket_cnt[i0 + k] : 0;
        tot += v[k];
    }
    sh[t] = tot;
    __syncthreads();
    for (int off = 1; off < 256; off <<= 1) {
        int add = (t >= off) ? sh[t - off] : 0;
        __syncthreads();
        sh[t] += add;
        __syncthreads();
    }
    int run = sh[t] - tot;
    for (int k = 0; k < 4; k++) {
        if (i0 + k < B) bucket_base[i0 + k] = run;
        run += v[k];
    }
    if (t == 0) bucket_base[B] = (int)E;
}

// Pass B: write packed edges to deterministic bucket slots.
__global__ void k_binB(const void* ei, long long E, const int* flag,
                       const int* block_cnt, const int* bucket_base,
                       unsigned* binned, int B) {
    extern __shared__ int cur[];
    int t = threadIdx.x, blk = blockIdx.x;
    for (int i = t; i < B; i += 256)
        cur[i] = bucket_base[i] + block_cnt[i * NBB + blk];
    __syncthreads();
    int f = *flag;
    long long chunk = (E + NBB - 1) / NBB;
    long long s = (long long)blk * chunk, e = min(E, s + chunk);
    if (f) {
        const long long* p = (const long long*)ei;
        for (long long i = s + t; i < e; i += 256) {
            int sv = (int)p[i], dv = (int)p[E + i];
            int slot = atomicAdd(&cur[dv >> 8], 1);
            binned[slot] = ((unsigned)sv << 8) | (unsigned)(dv & 255);
        }
    } else {
        const int* p = (const int*)ei;
        for (long long i = s + t; i < e; i += 256) {
            int sv = p[i], dv = p[E + i];
            int slot = atomicAdd(&cur[dv >> 8], 1);
            binned[slot] = ((unsigned)sv << 8) | (unsigned)(dv & 255);
        }
    }
}

// Per-bucket degree -> dinv, p1 = x * dinv.
__global__ void k_bucket_deg(const unsigned* binned, const int* bucket_base,
                             const float* x, float* dinv, float2* p1, int n) {
    __shared__ int hist[256];
    int t = threadIdx.x, b = blockIdx.x;
    hist[t] = 0;
    __syncthreads();
    int base = bucket_base[b], end = bucket_base[b + 1];
    for (int i = base + t; i < end; i += 256)
        atomicAdd(&hist[binned[i] & 255u], 1);
    __syncthreads();
    int v = b * 256 + t;
    if (v < n) {
        float dg = (float)(hist[t] + 1);  // +1 self loop
        float r = rsqrtf(dg);
        r = r * (1.5f - 0.5f * dg * r * r);  // Newton refine
        dinv[v] = r;
        p1[v] = make_float2(x[2 * v] * r, x[2 * v + 1] * r);
    }
}

// aggx = A_hat x (dim2, edge-parallel, LDS acc); fused layer1:
// p2 = relu(aggx@W1+b1)*dinv, stride 32, zero pad.
__global__ void k_agg2_l1(const float2* p1, const unsigned* binned,
                          const int* bucket_base, const float* dinv,
                          const float* W1, const float* b1,
                          float2* aggx, float* p2, int n) {
    __shared__ float acc2[512];
    int t = threadIdx.x, b = blockIdx.x;
    int v = b * 256 + t;
    if (v < n) {
        float2 q = p1[v];  // self loop
        acc2[2 * t] = q.x; acc2[2 * t + 1] = q.y;
    } else {
        acc2[2 * t] = 0.f; acc2[2 * t + 1] = 0.f;
    }
    __syncthreads();
    int base = bucket_base[b], end = bucket_base[b + 1];
    int i = base + t;
    for (; i + 768 < end; i += 1024) {
        unsigned e0 = binned[i], e1 = binned[i + 256], e2 = binned[i + 512], e3 = binned[i + 768];
        float2 q0 = p1[e0 >> 8], q1 = p1[e1 >> 8], q2 = p1[e2 >> 8], q3 = p1[e3 >> 8];
        atomicAdd(&acc2[2 * (e0 & 255u)], q0.x); atomicAdd(&acc2[2 * (e0 & 255u) + 1], q0.y);
        atomicAdd(&acc2[2 * (e1 & 255u)], q1.x); atomicAdd(&acc2[2 * (e1 & 255u) + 1], q1.y);
        atomicAdd(&acc2[2 * (e2 & 255u)], q2.x); atomicAdd(&acc2[2 * (e2 & 255u) + 1], q2.y);
        atomicAdd(&acc2[2 * (e3 & 255u)], q3.x); atomicAdd(&acc2[2 * (e3 & 255u) + 1], q3.y);
    }
    for (; i < end; i += 256) {
        unsigned e0 = binned[i];
        float2 q0 = p1[e0 >> 8];
        atomicAdd(&acc2[2 * (e0 & 255u)], q0.x);
        atomicAdd(&acc2[2 * (e0 & 255u) + 1], q0.y);
    }
    __syncthreads();
    if (v >= n) return;
    float r = dinv[v];
    float ax = acc2[2 * t] * r, ay = acc2[2 * t + 1] * r;
    aggx[v] = make_float2(ax, ay);
    float4 o[8];
    float* of = (float*)o;
#pragma unroll
    for (int j = 0; j < 30; j++)
        of[j] = fmaxf(fmaf(ax, W1[j], fmaf(ay, W1[30 + j], b1[j])), 0.f) * r;
    of[30] = 0.f; of[31] = 0.f;
    float4* d4 = (float4*)(p2 + (size_t)v * 32);
#pragma unroll
    for (int k = 0; k < 8; k++) d4[k] = o[k];
}

// Dim-30 aggregation (edge-parallel, one 32-lane group per edge, LDS acc
// stride 33) fused with layer2: h2 = relu((Ah1)W2[:30]+(Ax)W2[30:]+b2);
// p3 = ([h2,x]@W3)*dinv.
__global__ void k_agg30_l2(const float* p2, const unsigned* binned,
                           const int* bucket_base, const float2* aggx,
                           const float* x, const float* W2, const float* W3,
                           const float* b2, const float* dinv, float* p3, int n) {
    __shared__ float acc[256 * 33];
    __shared__ float W2s[960];
    __shared__ float W3s[32];
    __shared__ float b2s[30];
    int t = threadIdx.x, b = blockIdx.x;
    int g = t >> 5, j = t & 31;
    for (int i = t; i < 960; i += 256) W2s[i] = W2[i];
    if (t < 32) W3s[t] = W3[t];
    if (t < 30) b2s[t] = b2[t];
    for (int c = g; c < 256; c += 8) {  // self-loop init (pads are zero)
        int v = b * 256 + c;
        acc[c * 33 + j] = (v < n) ? p2[(size_t)v * 32 + j] : 0.f;
    }
    __syncthreads();
    int base = bucket_base[b], end = bucket_base[b + 1];
    int i = base + g;
    for (; i + 24 < end; i += 32) {
        unsigned e0 = binned[i], e1 = binned[i + 8], e2 = binned[i + 16], e3 = binned[i + 24];
        float v0 = p2[(size_t)(e0 >> 8) * 32 + j];
        float v1 = p2[(size_t)(e1 >> 8) * 32 + j];
        float v2 = p2[(size_t)(e2 >> 8) * 32 + j];
        float v3 = p2[(size_t)(e3 >> 8) * 32 + j];
        atomicAdd(&acc[(e0 & 255u) * 33 + j], v0);
        atomicAdd(&acc[(e1 & 255u) * 33 + j], v1);
        atomicAdd(&acc[(e2 & 255u) * 33 + j], v2);
        atomicAdd(&acc[(e3 & 255u) * 33 + j], v3);
    }
    for (; i < end; i += 8) {
        unsigned e0 = binned[i];
        atomicAdd(&acc[(e0 & 255u) * 33 + j], p2[(size_t)(e0 >> 8) * 32 + j]);
    }
    __syncthreads();
    int v = b * 256 + t;
    if (v >= n) return;
    float r = dinv[v];
    float2 a = aggx[v];
    float s[30];
#pragma unroll
    for (int jj = 0; jj < 30; jj++)
        s[jj] = fmaf(a.x, W2s[30 * 30 + jj], fmaf(a.y, W2s[31 * 30 + jj], b2s[jj]));
#pragma unroll
    for (int k = 0; k < 30; k++) {
        float hv = acc[t * 33 + k] * r;  // aggh_v[k]
#pragma unroll
        for (int jj = 0; jj < 30; jj++)
            s[jj] = fmaf(hv, W2s[k * 30 + jj], s[jj]);
    }
    float s3 = 0.f;
#pragma unroll
    for (int jj = 0; jj < 30; jj++) s3 = fmaf(fmaxf(s[jj], 0.f), W3s[jj], s3);
    s3 = fmaf(x[2 * v], W3s[30], s3);
    s3 = fmaf(x[2 * v + 1], W3s[31], s3);
    p3[v] = s3 * r;
}

// Dim-1 aggregation (edge-parallel, LDS acc) + bias -> out.
__global__ void k_agg1(const float* p3, const unsigned* binned,
                       const int* bucket_base, const float* dinv,
                       const float* b3, float* out, int n) {
    __shared__ float acc1[256];
    int t = threadIdx.x, b = blockIdx.x;
    int v = b * 256 + t;
    acc1[t] = (v < n) ? p3[v] : 0.f;  // self loop
    __syncthreads();
    int base = bucket_base[b], end = bucket_base[b + 1];
    int i = base + t;
    for (; i + 768 < end; i += 1024) {
        unsigned e0 = binned[i], e1 = binned[i + 256], e2 = binned[i + 512], e3 = binned[i + 768];
        float q0 = p3[e0 >> 8], q1 = p3[e1 >> 8], q2 = p3[e2 >> 8], q3 = p3[e3 >> 8];
        atomicAdd(&acc1[e0 & 255u], q0);
        atomicAdd(&acc1[e1 & 255u], q1);
        atomicAdd(&acc1[e2 & 255u], q2);
        atomicAdd(&acc1[e3 & 255u], q3);
    }
    for (; i < end; i += 256) {
        unsigned e0 = binned[i];
        atomicAdd(&acc1[e0 & 255u], p3[e0 >> 8]);
    }
    __syncthreads();
    if (v >= n) return;
    out[v] = fmaf(acc1[t], dinv[v], b3[0]);
}

extern "C" void kernel_launch(void* const* d_in, const int* in_sizes, int n_in,
                              void* d_out, int out_size, void* d_ws, size_t ws_size,
                              hipStream_t stream) {
    const float* x  = (const float*)d_in[0];
    const void*  ei = d_in[1];
    const float* W1 = (const float*)d_in[2];
    const float* b1 = (const float*)d_in[3];
    const float* W2 = (const float*)d_in[4];
    const float* b2 = (const float*)d_in[5];
    const float* W3 = (const float*)d_in[6];
    const float* b3 = (const float*)d_in[7];
    float* out = (float*)d_out;
    const int n = in_sizes[0] / 2;
    const long long E = in_sizes[1] / 2;
    const int B = (n + 255) / 256;  // dst buckets of 256 nodes

    char* w = (char*)d_ws;
    auto alloc = [&](size_t b) { void* p = (void*)w; w += (b + 255) & ~(size_t)255; return p; };
    int*      flag        = (int*)alloc(4);
    int*      block_cnt   = (int*)alloc((size_t)B * NBB * 4);
    int*      bucket_cnt  = (int*)alloc((size_t)B * 4);
    int*      bucket_base = (int*)alloc(((size_t)B + 1) * 4);
    unsigned* binned      = (unsigned*)alloc((size_t)E * 4);
    float*    dinv        = (float*)alloc((size_t)n * 4);
    float2*   p1          = (float2*)alloc((size_t)n * 8);
    float2*   aggx        = (float2*)alloc((size_t)n * 8);
    float*    p2          = (float*)alloc((size_t)n * 32 * 4);
    float*    p3          = (float*)alloc((size_t)n * 4);

    size_t lds = (size_t)B * 4;

    k_detect<<<1, 256, 0, stream>>>((const unsigned*)ei, flag);
    k_binA<<<NBB, 256, lds, stream>>>(ei, E, flag, block_cnt, B);
    k_colsum<<<B, 256, 0, stream>>>(block_cnt, bucket_cnt);
    k_bucketscan<<<1, 256, 0, stream>>>(bucket_cnt, bucket_base, B, E);
    k_binB<<<NBB, 256, lds, stream>>>(ei, E, flag, block_cnt, bucket_base, binned, B);
    k_bucket_deg<<<B, 256, 0, stream>>>(binned, bucket_base, x, dinv, p1, n);
    k_agg2_l1<<<B, 256, 0, stream>>>(p1, binned, bucket_base, dinv, W1, b1, aggx, p2, n);
    k_agg30_l2<<<B, 256, 0, stream>>>(p2, binned, bucket_base, aggx, x, W2, W3, b2, dinv, p3, n);
    k_agg1<<<B, 256, 0, stream>>>(p3, binned, bucket_base, dinv, b3, out, n);
}

// Round 5
// 320.516 us; speedup vs baseline: 2.8475x; 2.8475x over previous
//
#include <hip/hip_runtime.h>
#include <stdint.h>

// 3-layer GCN, gather-only aggregation off a per-node CSR (R1 structure,
// 403us, absmax 6e-5) + x8-unrolled gathers for memory-level parallelism.
// All edge-aggregation sums accumulate in FP64: the output threshold is
// ~1e-4 relative and fp32 summation-order noise through 3 chained
// aggregations was enough to fail (R3). fp64 acc makes accuracy
// order-independent; gathers stay fp32 loads (memory-bound, f64 adds free).
// CSR build = two-level counting sort, deterministic offsets, no global
// float atomics. binned[i] = (src<<8)|(dst&255), src < 2^18.

#define NBB 512  // binning blocks (2 per CU)

__global__ void k_detect(const unsigned* ei, int* flag) {
    __shared__ int nz;
    if (threadIdx.x == 0) nz = 0;
    __syncthreads();
    unsigned v = ei[2 * threadIdx.x + 1];
    if (v != 0) atomicAdd(&nz, 1);
    __syncthreads();
    if (threadIdx.x == 0) *flag = (nz == 0) ? 1 : 0;  // all-zero high words => int64
}

// Pass A: per-block bucket histogram -> block_cnt[bucket*NBB + blk]
__global__ void k_binA(const void* ei, long long E, const int* flag,
                       int* block_cnt, int B) {
    extern __shared__ int hist[];
    int t = threadIdx.x, blk = blockIdx.x;
    for (int i = t; i < B; i += 256) hist[i] = 0;
    __syncthreads();
    int f = *flag;
    long long chunk = (E + NBB - 1) / NBB;
    long long s = (long long)blk * chunk, e = min(E, s + chunk);
    if (f) {
        const long long* p = (const long long*)ei;
        for (long long i = s + t; i < e; i += 256)
            atomicAdd(&hist[((int)p[E + i]) >> 8], 1);
    } else {
        const int* p = (const int*)ei;
        for (long long i = s + t; i < e; i += 256)
            atomicAdd(&hist[p[E + i] >> 8], 1);
    }
    __syncthreads();
    for (int i = t; i < B; i += 256) block_cnt[i * NBB + blk] = hist[i];
}

// Per-bucket exclusive scan over the NBB block counts (in place); totals out.
__global__ void k_colsum(int* block_cnt, int* bucket_cnt) {
    __shared__ int sh[256];
    int t = threadIdx.x, b = blockIdx.x;
    int2 c = *(int2*)(block_cnt + (size_t)b * NBB + t * 2);
    int tot = c.x + c.y;
    sh[t] = tot;
    __syncthreads();
    for (int off = 1; off < 256; off <<= 1) {
        int add = (t >= off) ? sh[t - off] : 0;
        __syncthreads();
        sh[t] += add;
        __syncthreads();
    }
    int ex = sh[t] - tot;
    int2 o; o.x = ex; o.y = ex + c.x;
    *(int2*)(block_cnt + (size_t)b * NBB + t * 2) = o;
    if (t == 255) bucket_cnt[b] = sh[255];
}

// Exclusive scan over buckets -> bucket_base[0..B]; indptr[n]=E.
__global__ void k_bucketscan(const int* bucket_cnt, int* bucket_base, int B,
                             long long E, int* indptr, int n) {
    __shared__ int sh[256];
    int t = threadIdx.x;
    int i0 = t * 4;
    int v[4];
    int tot = 0;
    for (int k = 0; k < 4; k++) {
        v[k] = (i0 + k < B) ? bucket_cnt[i0 + k] : 0;
        tot += v[k];
    }
    sh[t] = tot;
    __syncthreads();
    for (int off = 1; off < 256; off <<= 1) {
        int add = (t >= off) ? sh[t - off] : 0;
        __syncthreads();
        sh[t] += add;
        __syncthreads();
    }
    int run = sh[t] - tot;
    for (int k = 0; k < 4; k++) {
        if (i0 + k < B) bucket_base[i0 + k] = run;
        run += v[k];
    }
    if (t == 0) { bucket_base[B] = (int)E; indptr[n] = (int)E; }
}

// Pass B: write packed edges to deterministic bucket slots.
__global__ void k_binB(const void* ei, long long E, const int* flag,
                       const int* block_cnt, const int* bucket_base,
                       unsigned* binned, int B) {
    extern __shared__ int cur[];
    int t = threadIdx.x, blk = blockIdx.x;
    for (int i = t; i < B; i += 256)
        cur[i] = bucket_base[i] + block_cnt[i * NBB + blk];
    __syncthreads();
    int f = *flag;
    long long chunk = (E + NBB - 1) / NBB;
    long long s = (long long)blk * chunk, e = min(E, s + chunk);
    if (f) {
        const long long* p = (const long long*)ei;
        for (long long i = s + t; i < e; i += 256) {
            int sv = (int)p[i], dv = (int)p[E + i];
            int slot = atomicAdd(&cur[dv >> 8], 1);
            binned[slot] = ((unsigned)sv << 8) | (unsigned)(dv & 255);
        }
    } else {
        const int* p = (const int*)ei;
        for (long long i = s + t; i < e; i += 256) {
            int sv = p[i], dv = p[E + i];
            int slot = atomicAdd(&cur[dv >> 8], 1);
            binned[slot] = ((unsigned)sv << 8) | (unsigned)(dv & 255);
        }
    }
}

// Per-bucket counting sort -> csr; also indptr, dinv, p1 = x*dinv.
__global__ void k_bucket_csr(const unsigned* binned, const int* bucket_base,
                             const float* x, int* indptr, float* dinv,
                             float2* p1, int* csr, int n) {
    __shared__ int hist[256], excl[256], cursor[256];
    int t = threadIdx.x, b = blockIdx.x;
    int base = bucket_base[b], end = bucket_base[b + 1];
    hist[t] = 0;
    __syncthreads();
    for (int i = base + t; i < end; i += 256)
        atomicAdd(&hist[binned[i] & 255u], 1);
    __syncthreads();
    int v = hist[t];
    excl[t] = v;
    __syncthreads();
    for (int off = 1; off < 256; off <<= 1) {
        int add = (t >= off) ? excl[t - off] : 0;
        __syncthreads();
        excl[t] += add;
        __syncthreads();
    }
    int ex = excl[t] - v;  // exclusive
    int node = b * 256 + t;
    if (node < n) {
        indptr[node] = base + ex;
        float dg = (float)(v + 1);
        float r = rsqrtf(dg);
        r = r * (1.5f - 0.5f * dg * r * r);
        dinv[node] = r;
        p1[node] = make_float2(x[2 * node] * r, x[2 * node + 1] * r);
    }
    cursor[t] = base + ex;
    __syncthreads();
    for (int i = base + t; i < end; i += 256) {
        unsigned p = binned[i];
        int slot = atomicAdd(&cursor[p & 255u], 1);
        csr[slot] = (int)(p >> 8);
    }
}

// Fused: aggx = A_hat x (dim2, x8 unroll, fp64 acc); p2 = relu(aggx@W1+b1)*dinv.
__global__ void k_agg2_l1(const float2* p1, const int* indptr, const int* csr,
                          const float* dinv, const float* W1, const float* b1,
                          float2* aggx, float* p2, int n) {
    int v = blockIdx.x * 256 + threadIdx.x;
    if (v >= n) return;
    float2 a0 = p1[v];
    double dax = a0.x, day = a0.y;
    int s = indptr[v], e = indptr[v + 1];
    int i = s;
    for (; i + 7 < e; i += 8) {
        int u0 = csr[i], u1 = csr[i + 1], u2 = csr[i + 2], u3 = csr[i + 3];
        int u4 = csr[i + 4], u5 = csr[i + 5], u6 = csr[i + 6], u7 = csr[i + 7];
        float2 q0 = p1[u0], q1 = p1[u1], q2 = p1[u2], q3 = p1[u3];
        float2 q4 = p1[u4], q5 = p1[u5], q6 = p1[u6], q7 = p1[u7];
        dax += ((double)q0.x + q1.x) + ((double)q2.x + q3.x) +
               ((double)q4.x + q5.x) + ((double)q6.x + q7.x);
        day += ((double)q0.y + q1.y) + ((double)q2.y + q3.y) +
               ((double)q4.y + q5.y) + ((double)q6.y + q7.y);
    }
    for (; i < e; i++) {
        float2 q = p1[csr[i]];
        dax += (double)q.x; day += (double)q.y;
    }
    float r = dinv[v];
    float ax = (float)(dax * (double)r), ay = (float)(day * (double)r);
    aggx[v] = make_float2(ax, ay);
    float4 o[8];
    float* of = (float*)o;
#pragma unroll
    for (int j = 0; j < 30; j++)
        of[j] = fmaxf(fmaf(ax, W1[j], fmaf(ay, W1[30 + j], b1[j])), 0.f) * r;
    of[30] = 0.f; of[31] = 0.f;
    float4* d4 = (float4*)(p2 + (size_t)v * 32);
#pragma unroll
    for (int k = 0; k < 8; k++) d4[k] = o[k];
}

// Dim-30 aggregation: 32-lane group per node, x8-unrolled independent 128B
// gathers, fp64 accumulator. aggh = dinv*(p2_self + sum p2_u).
__global__ void k_agg30(const float* p2, const int* indptr, const int* csr,
                        const float* dinv, float* aggh, int n) {
    int g = blockIdx.x * 8 + (threadIdx.x >> 5);
    int j = threadIdx.x & 31;
    if (g >= n) return;
    double acc = (double)p2[(size_t)g * 32 + j];  // self loop (pads read zero)
    int s = indptr[g], e = indptr[g + 1];
    int i = s;
    for (; i + 7 < e; i += 8) {
        int u0 = csr[i], u1 = csr[i + 1], u2 = csr[i + 2], u3 = csr[i + 3];
        int u4 = csr[i + 4], u5 = csr[i + 5], u6 = csr[i + 6], u7 = csr[i + 7];
        float f0 = p2[(size_t)u0 * 32 + j];
        float f1 = p2[(size_t)u1 * 32 + j];
        float f2 = p2[(size_t)u2 * 32 + j];
        float f3 = p2[(size_t)u3 * 32 + j];
        float f4 = p2[(size_t)u4 * 32 + j];
        float f5 = p2[(size_t)u5 * 32 + j];
        float f6 = p2[(size_t)u6 * 32 + j];
        float f7 = p2[(size_t)u7 * 32 + j];
        acc += ((double)f0 + f1) + ((double)f2 + f3) +
               ((double)f4 + f5) + ((double)f6 + f7);
    }
    for (; i < e; i++)
        acc += (double)p2[(size_t)csr[i] * 32 + j];
    if (j < 30) aggh[(size_t)g * 32 + j] = (float)(acc * (double)dinv[g]);
}

// h2 = relu((Ah1)W2[:30] + (Ax)W2[30:] + b2); p3 = ([h2,x]@W3) * dinv
// (exact R1 kernel — proven numerics)
__global__ void k_layer2(const float* aggh, const float2* aggx, const float* x,
                         const float* W2, const float* W3, const float* b2,
                         const float* dinv, float* p3, int n) {
    __shared__ float W2s[32 * 30];
    __shared__ float W3s[32];
    __shared__ float b2s[30];
    int t = threadIdx.x;
    for (int i = t; i < 960; i += 256) W2s[i] = W2[i];
    if (t < 32) W3s[t] = W3[t];
    if (t < 30) b2s[t] = b2[t];
    __syncthreads();
    int v = blockIdx.x * 256 + t;
    if (v >= n) return;
    float2 a = aggx[v];
    float acc[30];
#pragma unroll
    for (int j = 0; j < 30; j++)
        acc[j] = fmaf(a.x, W2s[30 * 30 + j], fmaf(a.y, W2s[31 * 30 + j], b2s[j]));
#pragma unroll
    for (int k = 0; k < 30; k++) {
        float hv = aggh[(size_t)v * 32 + k];
#pragma unroll
        for (int j = 0; j < 30; j++)
            acc[j] = fmaf(hv, W2s[k * 30 + j], acc[j]);
    }
    float s3 = 0.f;
#pragma unroll
    for (int j = 0; j < 30; j++) s3 = fmaf(fmaxf(acc[j], 0.f), W3s[j], s3);
    s3 = fmaf(x[2 * v], W3s[30], s3);
    s3 = fmaf(x[2 * v + 1], W3s[31], s3);
    p3[v] = s3 * dinv[v];
}

// out_v = dinv_v * (p3_v + sum p3_u) + b3   (dim 1, x8 unroll, fp64 acc)
__global__ void k_agg1(const float* p3, const int* indptr, const int* csr,
                       const float* dinv, const float* b3, float* out, int n) {
    int v = blockIdx.x * 256 + threadIdx.x;
    if (v >= n) return;
    double acc = (double)p3[v];
    int s = indptr[v], e = indptr[v + 1];
    int i = s;
    for (; i + 7 < e; i += 8) {
        int u0 = csr[i], u1 = csr[i + 1], u2 = csr[i + 2], u3 = csr[i + 3];
        int u4 = csr[i + 4], u5 = csr[i + 5], u6 = csr[i + 6], u7 = csr[i + 7];
        float f0 = p3[u0], f1 = p3[u1], f2 = p3[u2], f3 = p3[u3];
        float f4 = p3[u4], f5 = p3[u5], f6 = p3[u6], f7 = p3[u7];
        acc += ((double)f0 + f1) + ((double)f2 + f3) +
               ((double)f4 + f5) + ((double)f6 + f7);
    }
    for (; i < e; i++) acc += (double)p3[csr[i]];
    out[v] = (float)(acc * (double)dinv[v] + (double)b3[0]);
}

extern "C" void kernel_launch(void* const* d_in, const int* in_sizes, int n_in,
                              void* d_out, int out_size, void* d_ws, size_t ws_size,
                              hipStream_t stream) {
    const float* x  = (const float*)d_in[0];
    const void*  ei = d_in[1];
    const float* W1 = (const float*)d_in[2];
    const float* b1 = (const float*)d_in[3];
    const float* W2 = (const float*)d_in[4];
    const float* b2 = (const float*)d_in[5];
    const float* W3 = (const float*)d_in[6];
    const float* b3 = (const float*)d_in[7];
    float* out = (float*)d_out;
    const int n = in_sizes[0] / 2;
    const long long E = in_sizes[1] / 2;
    const int B = (n + 255) / 256;  // dst buckets of 256 nodes

    char* w = (char*)d_ws;
    auto alloc = [&](size_t b) { void* p = (void*)w; w += (b + 255) & ~(size_t)255; return p; };
    int*      flag        = (int*)alloc(4);
    int*      block_cnt   = (int*)alloc((size_t)B * NBB * 4);
    int*      bucket_cnt  = (int*)alloc((size_t)B * 4);
    int*      bucket_base = (int*)alloc(((size_t)B + 1) * 4);
    unsigned* binned      = (unsigned*)alloc((size_t)E * 4);
    int*      indptr      = (int*)alloc(((size_t)n + 1) * 4);
    float*    dinv        = (float*)alloc((size_t)n * 4);
    int*      csr         = (int*)alloc((size_t)E * 4);
    float2*   p1          = (float2*)alloc((size_t)n * 8);
    float2*   aggx        = (float2*)alloc((size_t)n * 8);
    float*    p2          = (float*)alloc((size_t)n * 32 * 4);
    float*    aggh        = (float*)alloc((size_t)n * 32 * 4);
    float*    p3          = (float*)alloc((size_t)n * 4);

    int nblocks = (n + 255) / 256;
    size_t lds = (size_t)B * 4;

    k_detect<<<1, 256, 0, stream>>>((const unsigned*)ei, flag);
    k_binA<<<NBB, 256, lds, stream>>>(ei, E, flag, block_cnt, B);
    k_colsum<<<B, 256, 0, stream>>>(block_cnt, bucket_cnt);
    k_bucketscan<<<1, 256, 0, stream>>>(bucket_cnt, bucket_base, B, E, indptr, n);
    k_binB<<<NBB, 256, lds, stream>>>(ei, E, flag, block_cnt, bucket_base, binned, B);
    k_bucket_csr<<<B, 256, 0, stream>>>(binned, bucket_base, x, indptr, dinv, p1, csr, n);
    k_agg2_l1<<<nblocks, 256, 0, stream>>>(p1, indptr, csr, dinv, W1, b1, aggx, p2, n);
    k_agg30<<<(n + 7) / 8, 256, 0, stream>>>(p2, indptr, csr, dinv, aggh, n);
    k_layer2<<<nblocks, 256, 0, stream>>>(aggh, aggx, x, W2, W3, b2, dinv, p3, n);
    k_agg1<<<nblocks, 256, 0, stream>>>(p3, indptr, csr, dinv, b3, out, n);
}

// Round 6
// 304.473 us; speedup vs baseline: 2.9975x; 1.0527x over previous
//
#include <hip/hip_runtime.h>
#include <stdint.h>

// 3-layer GCN, gather-only aggregation off a per-node CSR. R4 (320us) +
// bf16 compression of the dim-30 intermediates (p2, aggh): the dim-30
// gather is 64B-sector-throughput-bound, so halving row bytes 128->64B
// halves its sector traffic. Aggregation accumulators stay FP64 (accuracy
// is order-independent; threshold is ~2% relative, bf16 intermediates cost
// ~1e-3 abs). k_detect folded into binA/binB as per-block dtype checks.
// CSR build = two-level counting sort, deterministic offsets, no global
// float atomics. binned[i] = (src<<8)|(dst&255), src < 2^18.

#define NBB 512  // binning blocks (2 per CU)

__device__ __forceinline__ unsigned short f2bf(float f) {  // RNE, no NaN inputs
    unsigned u = __float_as_uint(f);
    unsigned r = ((u >> 16) & 1u) + 0x7FFFu;
    return (unsigned short)((u + r) >> 16);
}
__device__ __forceinline__ float bf2f(unsigned short h) {
    return __uint_as_float((unsigned)h << 16);
}

// Per-block int64-vs-int32 detect: int64 edge values < 2^18 => all high
// words zero; int32 data at those offsets is src[i], almost surely nonzero.
__device__ __forceinline__ int detect64(const unsigned* ei, int* s_nz, int t) {
    unsigned v = ei[2 * t + 1];
    if (v != 0) atomicAdd(s_nz, 1);
    __syncthreads();
    return (*s_nz == 0);
}

// Pass A: per-block bucket histogram -> block_cnt[bucket*NBB + blk]
__global__ void k_binA(const void* ei, long long E, int* block_cnt, int B) {
    extern __shared__ int hist[];
    __shared__ int s_nz;
    int t = threadIdx.x, blk = blockIdx.x;
    if (t == 0) s_nz = 0;
    for (int i = t; i < B; i += 256) hist[i] = 0;
    __syncthreads();
    int f = detect64((const unsigned*)ei, &s_nz, t);
    long long chunk = (E + NBB - 1) / NBB;
    long long s = (long long)blk * chunk, e = min(E, s + chunk);
    if (f) {
        const long long* p = (const long long*)ei;
        for (long long i = s + t; i < e; i += 256)
            atomicAdd(&hist[((int)p[E + i]) >> 8], 1);
    } else {
        const int* p = (const int*)ei;
        for (long long i = s + t; i < e; i += 256)
            atomicAdd(&hist[p[E + i] >> 8], 1);
    }
    __syncthreads();
    for (int i = t; i < B; i += 256) block_cnt[i * NBB + blk] = hist[i];
}

// Per-bucket exclusive scan over the NBB block counts (in place); totals out.
__global__ void k_colsum(int* block_cnt, int* bucket_cnt) {
    __shared__ int sh[256];
    int t = threadIdx.x, b = blockIdx.x;
    int2 c = *(int2*)(block_cnt + (size_t)b * NBB + t * 2);
    int tot = c.x + c.y;
    sh[t] = tot;
    __syncthreads();
    for (int off = 1; off < 256; off <<= 1) {
        int add = (t >= off) ? sh[t - off] : 0;
        __syncthreads();
        sh[t] += add;
        __syncthreads();
    }
    int ex = sh[t] - tot;
    int2 o; o.x = ex; o.y = ex + c.x;
    *(int2*)(block_cnt + (size_t)b * NBB + t * 2) = o;
    if (t == 255) bucket_cnt[b] = sh[255];
}

// Exclusive scan over buckets -> bucket_base[0..B]; indptr[n]=E.
__global__ void k_bucketscan(const int* bucket_cnt, int* bucket_base, int B,
                             long long E, int* indptr, int n) {
    __shared__ int sh[256];
    int t = threadIdx.x;
    int i0 = t * 4;
    int v[4];
    int tot = 0;
    for (int k = 0; k < 4; k++) {
        v[k] = (i0 + k < B) ? bucket_cnt[i0 + k] : 0;
        tot += v[k];
    }
    sh[t] = tot;
    __syncthreads();
    for (int off = 1; off < 256; off <<= 1) {
        int add = (t >= off) ? sh[t - off] : 0;
        __syncthreads();
        sh[t] += add;
        __syncthreads();
    }
    int run = sh[t] - tot;
    for (int k = 0; k < 4; k++) {
        if (i0 + k < B) bucket_base[i0 + k] = run;
        run += v[k];
    }
    if (t == 0) { bucket_base[B] = (int)E; indptr[n] = (int)E; }
}

// Pass B: write packed edges to deterministic bucket slots.
__global__ void k_binB(const void* ei, long long E, const int* block_cnt,
                       const int* bucket_base, unsigned* binned, int B) {
    extern __shared__ int cur[];
    __shared__ int s_nz;
    int t = threadIdx.x, blk = blockIdx.x;
    if (t == 0) s_nz = 0;
    for (int i = t; i < B; i += 256)
        cur[i] = bucket_base[i] + block_cnt[i * NBB + blk];
    __syncthreads();
    int f = detect64((const unsigned*)ei, &s_nz, t);
    long long chunk = (E + NBB - 1) / NBB;
    long long s = (long long)blk * chunk, e = min(E, s + chunk);
    if (f) {
        const long long* p = (const long long*)ei;
        for (long long i = s + t; i < e; i += 256) {
            int sv = (int)p[i], dv = (int)p[E + i];
            int slot = atomicAdd(&cur[dv >> 8], 1);
            binned[slot] = ((unsigned)sv << 8) | (unsigned)(dv & 255);
        }
    } else {
        const int* p = (const int*)ei;
        for (long long i = s + t; i < e; i += 256) {
            int sv = p[i], dv = p[E + i];
            int slot = atomicAdd(&cur[dv >> 8], 1);
            binned[slot] = ((unsigned)sv << 8) | (unsigned)(dv & 255);
        }
    }
}

// Per-bucket counting sort -> csr; also indptr, dinv, p1 = x*dinv.
__global__ void k_bucket_csr(const unsigned* binned, const int* bucket_base,
                             const float* x, int* indptr, float* dinv,
                             float2* p1, int* csr, int n) {
    __shared__ int hist[256], excl[256], cursor[256];
    int t = threadIdx.x, b = blockIdx.x;
    int base = bucket_base[b], end = bucket_base[b + 1];
    hist[t] = 0;
    __syncthreads();
    for (int i = base + t; i < end; i += 256)
        atomicAdd(&hist[binned[i] & 255u], 1);
    __syncthreads();
    int v = hist[t];
    excl[t] = v;
    __syncthreads();
    for (int off = 1; off < 256; off <<= 1) {
        int add = (t >= off) ? excl[t - off] : 0;
        __syncthreads();
        excl[t] += add;
        __syncthreads();
    }
    int ex = excl[t] - v;  // exclusive
    int node = b * 256 + t;
    if (node < n) {
        indptr[node] = base + ex;
        float dg = (float)(v + 1);
        float r = rsqrtf(dg);
        r = r * (1.5f - 0.5f * dg * r * r);
        dinv[node] = r;
        p1[node] = make_float2(x[2 * node] * r, x[2 * node + 1] * r);
    }
    cursor[t] = base + ex;
    __syncthreads();
    for (int i = base + t; i < end; i += 256) {
        unsigned p = binned[i];
        int slot = atomicAdd(&cursor[p & 255u], 1);
        csr[slot] = (int)(p >> 8);
    }
}

// Fused: aggx = A_hat x (dim2, x8 unroll, fp64 acc);
// p2 = bf16(relu(aggx@W1+b1)*dinv), 64B rows (32 ushorts, 2 zero pads).
__global__ void k_agg2_l1(const float2* p1, const int* indptr, const int* csr,
                          const float* dinv, const float* W1, const float* b1,
                          float2* aggx, unsigned short* p2, int n) {
    int v = blockIdx.x * 256 + threadIdx.x;
    if (v >= n) return;
    float2 a0 = p1[v];
    double dax = a0.x, day = a0.y;
    int s = indptr[v], e = indptr[v + 1];
    int i = s;
    for (; i + 7 < e; i += 8) {
        int u0 = csr[i], u1 = csr[i + 1], u2 = csr[i + 2], u3 = csr[i + 3];
        int u4 = csr[i + 4], u5 = csr[i + 5], u6 = csr[i + 6], u7 = csr[i + 7];
        float2 q0 = p1[u0], q1 = p1[u1], q2 = p1[u2], q3 = p1[u3];
        float2 q4 = p1[u4], q5 = p1[u5], q6 = p1[u6], q7 = p1[u7];
        dax += ((double)q0.x + q1.x) + ((double)q2.x + q3.x) +
               ((double)q4.x + q5.x) + ((double)q6.x + q7.x);
        day += ((double)q0.y + q1.y) + ((double)q2.y + q3.y) +
               ((double)q4.y + q5.y) + ((double)q6.y + q7.y);
    }
    for (; i < e; i++) {
        float2 q = p1[csr[i]];
        dax += (double)q.x; day += (double)q.y;
    }
    float r = dinv[v];
    float ax = (float)(dax * (double)r), ay = (float)(day * (double)r);
    aggx[v] = make_float2(ax, ay);
    __align__(16) unsigned short ob[32];
#pragma unroll
    for (int j = 0; j < 30; j++)
        ob[j] = f2bf(fmaxf(fmaf(ax, W1[j], fmaf(ay, W1[30 + j], b1[j])), 0.f) * r);
    ob[30] = 0; ob[31] = 0;
    uint4* d4 = (uint4*)(p2 + (size_t)v * 32);
    const uint4* s4 = (const uint4*)ob;
#pragma unroll
    for (int k = 0; k < 4; k++) d4[k] = s4[k];
}

// Dim-30 aggregation: 32-lane group per node, x8-unrolled independent 64B
// bf16-row gathers, fp64 accumulator. aggh = bf16(dinv*(p2_self + sum p2_u)).
__global__ void k_agg30(const unsigned short* p2, const int* indptr,
                        const int* csr, const float* dinv,
                        unsigned short* aggh, int n) {
    int g = blockIdx.x * 8 + (threadIdx.x >> 5);
    int j = threadIdx.x & 31;
    if (g >= n) return;
    double acc = (double)bf2f(p2[(size_t)g * 32 + j]);  // self loop (pads zero)
    int s = indptr[g], e = indptr[g + 1];
    int i = s;
    for (; i + 7 < e; i += 8) {
        int u0 = csr[i], u1 = csr[i + 1], u2 = csr[i + 2], u3 = csr[i + 3];
        int u4 = csr[i + 4], u5 = csr[i + 5], u6 = csr[i + 6], u7 = csr[i + 7];
        float f0 = bf2f(p2[(size_t)u0 * 32 + j]);
        float f1 = bf2f(p2[(size_t)u1 * 32 + j]);
        float f2 = bf2f(p2[(size_t)u2 * 32 + j]);
        float f3 = bf2f(p2[(size_t)u3 * 32 + j]);
        float f4 = bf2f(p2[(size_t)u4 * 32 + j]);
        float f5 = bf2f(p2[(size_t)u5 * 32 + j]);
        float f6 = bf2f(p2[(size_t)u6 * 32 + j]);
        float f7 = bf2f(p2[(size_t)u7 * 32 + j]);
        acc += ((double)f0 + f1) + ((double)f2 + f3) +
               ((double)f4 + f5) + ((double)f6 + f7);
    }
    for (; i < e; i++)
        acc += (double)bf2f(p2[(size_t)csr[i] * 32 + j]);
    if (j < 30) aggh[(size_t)g * 32 + j] = f2bf((float)(acc * (double)dinv[g]));
}

// h2 = relu((Ah1)W2[:30] + (Ax)W2[30:] + b2); p3 = ([h2,x]@W3) * dinv.
// Block stages its 256 bf16 aggh rows through LDS (stride-17 uints,
// conflict-free) so global reads stay coalesced.
__global__ void k_layer2(const unsigned short* aggh, const float2* aggx,
                         const float* x, const float* W2, const float* W3,
                         const float* b2, const float* dinv, float* p3, int n) {
    __shared__ float W2s[32 * 30];
    __shared__ float W3s[32];
    __shared__ float b2s[30];
    __shared__ unsigned hsh[256 * 17];
    int t = threadIdx.x;
    for (int i = t; i < 960; i += 256) W2s[i] = W2[i];
    if (t < 32) W3s[t] = W3[t];
    if (t < 30) b2s[t] = b2[t];
    const unsigned* ag = (const unsigned*)aggh + (size_t)blockIdx.x * 256 * 16;
    int rows = min(256, n - blockIdx.x * 256);
    for (int i = t; i < rows * 16; i += 256) {
        int rr = i >> 4, cc = i & 15;
        hsh[rr * 17 + cc] = ag[i];
    }
    __syncthreads();
    int v = blockIdx.x * 256 + t;
    if (v >= n) return;
    float2 a = aggx[v];
    float acc[30];
#pragma unroll
    for (int j = 0; j < 30; j++)
        acc[j] = fmaf(a.x, W2s[30 * 30 + j], fmaf(a.y, W2s[31 * 30 + j], b2s[j]));
#pragma unroll
    for (int kk = 0; kk < 15; kk++) {  // 30 values = 15 uint pairs
        unsigned pr = hsh[t * 17 + kk];
        float h0 = bf2f((unsigned short)(pr & 0xFFFFu));
        float h1v = bf2f((unsigned short)(pr >> 16));
#pragma unroll
        for (int j = 0; j < 30; j++)
            acc[j] = fmaf(h0, W2s[(2 * kk) * 30 + j], acc[j]);
#pragma unroll
        for (int j = 0; j < 30; j++)
            acc[j] = fmaf(h1v, W2s[(2 * kk + 1) * 30 + j], acc[j]);
    }
    float s3 = 0.f;
#pragma unroll
    for (int j = 0; j < 30; j++) s3 = fmaf(fmaxf(acc[j], 0.f), W3s[j], s3);
    s3 = fmaf(x[2 * v], W3s[30], s3);
    s3 = fmaf(x[2 * v + 1], W3s[31], s3);
    p3[v] = s3 * dinv[v];
}

// out_v = dinv_v * (p3_v + sum p3_u) + b3   (dim 1, x8 unroll, fp64 acc)
__global__ void k_agg1(const float* p3, const int* indptr, const int* csr,
                       const float* dinv, const float* b3, float* out, int n) {
    int v = blockIdx.x * 256 + threadIdx.x;
    if (v >= n) return;
    double acc = (double)p3[v];
    int s = indptr[v], e = indptr[v + 1];
    int i = s;
    for (; i + 7 < e; i += 8) {
        int u0 = csr[i], u1 = csr[i + 1], u2 = csr[i + 2], u3 = csr[i + 3];
        int u4 = csr[i + 4], u5 = csr[i + 5], u6 = csr[i + 6], u7 = csr[i + 7];
        float f0 = p3[u0], f1 = p3[u1], f2 = p3[u2], f3 = p3[u3];
        float f4 = p3[u4], f5 = p3[u5], f6 = p3[u6], f7 = p3[u7];
        acc += ((double)f0 + f1) + ((double)f2 + f3) +
               ((double)f4 + f5) + ((double)f6 + f7);
    }
    for (; i < e; i++) acc += (double)p3[csr[i]];
    out[v] = (float)(acc * (double)dinv[v] + (double)b3[0]);
}

extern "C" void kernel_launch(void* const* d_in, const int* in_sizes, int n_in,
                              void* d_out, int out_size, void* d_ws, size_t ws_size,
                              hipStream_t stream) {
    const float* x  = (const float*)d_in[0];
    const void*  ei = d_in[1];
    const float* W1 = (const float*)d_in[2];
    const float* b1 = (const float*)d_in[3];
    const float* W2 = (const float*)d_in[4];
    const float* b2 = (const float*)d_in[5];
    const float* W3 = (const float*)d_in[6];
    const float* b3 = (const float*)d_in[7];
    float* out = (float*)d_out;
    const int n = in_sizes[0] / 2;
    const long long E = in_sizes[1] / 2;
    const int B = (n + 255) / 256;  // dst buckets of 256 nodes

    char* w = (char*)d_ws;
    auto alloc = [&](size_t b) { void* p = (void*)w; w += (b + 255) & ~(size_t)255; return p; };
    int*            block_cnt   = (int*)alloc((size_t)B * NBB * 4);
    int*            bucket_cnt  = (int*)alloc((size_t)B * 4);
    int*            bucket_base = (int*)alloc(((size_t)B + 1) * 4);
    unsigned*       binned      = (unsigned*)alloc((size_t)E * 4);
    int*            indptr      = (int*)alloc(((size_t)n + 1) * 4);
    float*          dinv        = (float*)alloc((size_t)n * 4);
    int*            csr         = (int*)alloc((size_t)E * 4);
    float2*         p1          = (float2*)alloc((size_t)n * 8);
    float2*         aggx        = (float2*)alloc((size_t)n * 8);
    unsigned short* p2          = (unsigned short*)alloc((size_t)n * 32 * 2);
    unsigned short* aggh        = (unsigned short*)alloc((size_t)n * 32 * 2);
    float*          p3          = (float*)alloc((size_t)n * 4);

    int nblocks = (n + 255) / 256;
    size_t lds = (size_t)B * 4;

    k_binA<<<NBB, 256, lds, stream>>>(ei, E, block_cnt, B);
    k_colsum<<<B, 256, 0, stream>>>(block_cnt, bucket_cnt);
    k_bucketscan<<<1, 256, 0, stream>>>(bucket_cnt, bucket_base, B, E, indptr, n);
    k_binB<<<NBB, 256, lds, stream>>>(ei, E, block_cnt, bucket_base, binned, B);
    k_bucket_csr<<<B, 256, 0, stream>>>(binned, bucket_base, x, indptr, dinv, p1, csr, n);
    k_agg2_l1<<<nblocks, 256, 0, stream>>>(p1, indptr, csr, dinv, W1, b1, aggx, p2, n);
    k_agg30<<<(n + 7) / 8, 256, 0, stream>>>(p2, indptr, csr, dinv, aggh, n);
    k_layer2<<<nblocks, 256, 0, stream>>>(aggh, aggx, x, W2, W3, b2, dinv, p3, n);
    k_agg1<<<nblocks, 256, 0, stream>>>(p3, indptr, csr, dinv, b3, out, n);
}

// Round 7
// 274.361 us; speedup vs baseline: 3.3265x; 1.1098x over previous
//
#include <hip/hip_runtime.h>
#include <stdint.h>

// 3-layer GCN, gather-only aggregation off a per-node CSR. R5 (304us) +
// (1) source-tiled CSR: each node's edge list is counting-sorted by
//     src>>15 (8 tiles x 2MB of p2) so all gather kernels sweep source
//     tiles roughly in phase -> smaller instantaneous working set -> L2
//     hits instead of L3 requests (k_agg30 is request-rate-bound).
// (2) k_agg30 uses 16-lane groups loading ushort2: 4 nodes/wave, 2x the
//     loads in flight, half the VMEM instructions.
// Aggregation accumulators FP64 (order-independent accuracy); dim-30
// intermediates bf16 (64B rows). CSR build = two-level counting sort,
// deterministic offsets, no global float atomics.
// binned[i] = (src<<8)|(dst&255), src < 2^18.

#define NBB 512  // binning blocks (2 per CU)

__device__ __forceinline__ unsigned short f2bf(float f) {  // RNE, no NaN inputs
    unsigned u = __float_as_uint(f);
    unsigned r = ((u >> 16) & 1u) + 0x7FFFu;
    return (unsigned short)((u + r) >> 16);
}
__device__ __forceinline__ float bf2f(unsigned short h) {
    return __uint_as_float((unsigned)h << 16);
}

// Per-block int64-vs-int32 detect: int64 edge values < 2^18 => all high
// words zero; int32 data at those offsets is src[i], almost surely nonzero.
__device__ __forceinline__ int detect64(const unsigned* ei, int* s_nz, int t) {
    unsigned v = ei[2 * t + 1];
    if (v != 0) atomicAdd(s_nz, 1);
    __syncthreads();
    return (*s_nz == 0);
}

// Pass A: per-block bucket histogram -> block_cnt[bucket*NBB + blk]
__global__ void k_binA(const void* ei, long long E, int* block_cnt, int B) {
    extern __shared__ int hist[];
    __shared__ int s_nz;
    int t = threadIdx.x, blk = blockIdx.x;
    if (t == 0) s_nz = 0;
    for (int i = t; i < B; i += 256) hist[i] = 0;
    __syncthreads();
    int f = detect64((const unsigned*)ei, &s_nz, t);
    long long chunk = (E + NBB - 1) / NBB;
    long long s = (long long)blk * chunk, e = min(E, s + chunk);
    if (f) {
        const long long* p = (const long long*)ei;
        for (long long i = s + t; i < e; i += 256)
            atomicAdd(&hist[((int)p[E + i]) >> 8], 1);
    } else {
        const int* p = (const int*)ei;
        for (long long i = s + t; i < e; i += 256)
            atomicAdd(&hist[p[E + i] >> 8], 1);
    }
    __syncthreads();
    for (int i = t; i < B; i += 256) block_cnt[i * NBB + blk] = hist[i];
}

// Per-bucket exclusive scan over the NBB block counts (in place); totals out.
__global__ void k_colsum(int* block_cnt, int* bucket_cnt) {
    __shared__ int sh[256];
    int t = threadIdx.x, b = blockIdx.x;
    int2 c = *(int2*)(block_cnt + (size_t)b * NBB + t * 2);
    int tot = c.x + c.y;
    sh[t] = tot;
    __syncthreads();
    for (int off = 1; off < 256; off <<= 1) {
        int add = (t >= off) ? sh[t - off] : 0;
        __syncthreads();
        sh[t] += add;
        __syncthreads();
    }
    int ex = sh[t] - tot;
    int2 o; o.x = ex; o.y = ex + c.x;
    *(int2*)(block_cnt + (size_t)b * NBB + t * 2) = o;
    if (t == 255) bucket_cnt[b] = sh[255];
}

// Exclusive scan over buckets -> bucket_base[0..B]; indptr[n]=E.
__global__ void k_bucketscan(const int* bucket_cnt, int* bucket_base, int B,
                             long long E, int* indptr, int n) {
    __shared__ int sh[256];
    int t = threadIdx.x;
    int i0 = t * 4;
    int v[4];
    int tot = 0;
    for (int k = 0; k < 4; k++) {
        v[k] = (i0 + k < B) ? bucket_cnt[i0 + k] : 0;
        tot += v[k];
    }
    sh[t] = tot;
    __syncthreads();
    for (int off = 1; off < 256; off <<= 1) {
        int add = (t >= off) ? sh[t - off] : 0;
        __syncthreads();
        sh[t] += add;
        __syncthreads();
    }
    int run = sh[t] - tot;
    for (int k = 0; k < 4; k++) {
        if (i0 + k < B) bucket_base[i0 + k] = run;
        run += v[k];
    }
    if (t == 0) { bucket_base[B] = (int)E; indptr[n] = (int)E; }
}

// Pass B: write packed edges to deterministic bucket slots.
__global__ void k_binB(const void* ei, long long E, const int* block_cnt,
                       const int* bucket_base, unsigned* binned, int B) {
    extern __shared__ int cur[];
    __shared__ int s_nz;
    int t = threadIdx.x, blk = blockIdx.x;
    if (t == 0) s_nz = 0;
    for (int i = t; i < B; i += 256)
        cur[i] = bucket_base[i] + block_cnt[i * NBB + blk];
    __syncthreads();
    int f = detect64((const unsigned*)ei, &s_nz, t);
    long long chunk = (E + NBB - 1) / NBB;
    long long s = (long long)blk * chunk, e = min(E, s + chunk);
    if (f) {
        const long long* p = (const long long*)ei;
        for (long long i = s + t; i < e; i += 256) {
            int sv = (int)p[i], dv = (int)p[E + i];
            int slot = atomicAdd(&cur[dv >> 8], 1);
            binned[slot] = ((unsigned)sv << 8) | (unsigned)(dv & 255);
        }
    } else {
        const int* p = (const int*)ei;
        for (long long i = s + t; i < e; i += 256) {
            int sv = p[i], dv = p[E + i];
            int slot = atomicAdd(&cur[dv >> 8], 1);
            binned[slot] = ((unsigned)sv << 8) | (unsigned)(dv & 255);
        }
    }
}

// Per-bucket counting sort by (node, src>>15) -> csr tile-grouped per node;
// also indptr, dinv, p1 = x*dinv.
__global__ void k_bucket_csr(const unsigned* binned, const int* bucket_base,
                             const float* x, int* indptr, float* dinv,
                             float2* p1, int* csr, int n) {
    __shared__ int hist2[256 * 8];   // [node][tile]
    __shared__ int cursor2[256 * 8];
    __shared__ int excl[256];
    int t = threadIdx.x, b = blockIdx.x;
    int base = bucket_base[b], end = bucket_base[b + 1];
#pragma unroll
    for (int k = 0; k < 8; k++) hist2[t * 8 + k] = 0;
    __syncthreads();
    for (int i = base + t; i < end; i += 256) {
        unsigned p = binned[i];
        unsigned src = p >> 8;
        atomicAdd(&hist2[(p & 255u) * 8 + (src >> 15)], 1);
    }
    __syncthreads();
    int tot = 0;
#pragma unroll
    for (int k = 0; k < 8; k++) tot += hist2[t * 8 + k];
    excl[t] = tot;
    __syncthreads();
    for (int off = 1; off < 256; off <<= 1) {
        int add = (t >= off) ? excl[t - off] : 0;
        __syncthreads();
        excl[t] += add;
        __syncthreads();
    }
    int nodebase = base + excl[t] - tot;  // exclusive
    int run = nodebase;
#pragma unroll
    for (int k = 0; k < 8; k++) {
        cursor2[t * 8 + k] = run;
        run += hist2[t * 8 + k];
    }
    int node = b * 256 + t;
    if (node < n) {
        indptr[node] = nodebase;
        float dg = (float)(tot + 1);
        float r = rsqrtf(dg);
        r = r * (1.5f - 0.5f * dg * r * r);
        dinv[node] = r;
        p1[node] = make_float2(x[2 * node] * r, x[2 * node + 1] * r);
    }
    __syncthreads();
    for (int i = base + t; i < end; i += 256) {
        unsigned p = binned[i];
        unsigned src = p >> 8;
        int slot = atomicAdd(&cursor2[(p & 255u) * 8 + (src >> 15)], 1);
        csr[slot] = (int)src;
    }
}

// Fused: aggx = A_hat x (dim2, x8 unroll, fp64 acc);
// p2 = bf16(relu(aggx@W1+b1)*dinv), 64B rows (32 ushorts, 2 zero pads).
__global__ void k_agg2_l1(const float2* p1, const int* indptr, const int* csr,
                          const float* dinv, const float* W1, const float* b1,
                          float2* aggx, unsigned short* p2, int n) {
    int v = blockIdx.x * 256 + threadIdx.x;
    if (v >= n) return;
    float2 a0 = p1[v];
    double dax = a0.x, day = a0.y;
    int s = indptr[v], e = indptr[v + 1];
    int i = s;
    for (; i + 7 < e; i += 8) {
        int u0 = csr[i], u1 = csr[i + 1], u2 = csr[i + 2], u3 = csr[i + 3];
        int u4 = csr[i + 4], u5 = csr[i + 5], u6 = csr[i + 6], u7 = csr[i + 7];
        float2 q0 = p1[u0], q1 = p1[u1], q2 = p1[u2], q3 = p1[u3];
        float2 q4 = p1[u4], q5 = p1[u5], q6 = p1[u6], q7 = p1[u7];
        dax += ((double)q0.x + q1.x) + ((double)q2.x + q3.x) +
               ((double)q4.x + q5.x) + ((double)q6.x + q7.x);
        day += ((double)q0.y + q1.y) + ((double)q2.y + q3.y) +
               ((double)q4.y + q5.y) + ((double)q6.y + q7.y);
    }
    for (; i < e; i++) {
        float2 q = p1[csr[i]];
        dax += (double)q.x; day += (double)q.y;
    }
    float r = dinv[v];
    float ax = (float)(dax * (double)r), ay = (float)(day * (double)r);
    aggx[v] = make_float2(ax, ay);
    __align__(16) unsigned short ob[32];
#pragma unroll
    for (int j = 0; j < 30; j++)
        ob[j] = f2bf(fmaxf(fmaf(ax, W1[j], fmaf(ay, W1[30 + j], b1[j])), 0.f) * r);
    ob[30] = 0; ob[31] = 0;
    uint4* d4 = (uint4*)(p2 + (size_t)v * 32);
    const uint4* s4 = (const uint4*)ob;
#pragma unroll
    for (int k = 0; k < 4; k++) d4[k] = s4[k];
}

// Dim-30 aggregation: 16-lane group per node, each lane holds a bf16 pair
// (ushort2 load = 64B/row/group), x8-unrolled independent gathers, fp64
// accumulators. aggh = bf16(dinv*(p2_self + sum p2_u)).
__global__ void k_agg30(const unsigned* p2u, const int* indptr,
                        const int* csr, const float* dinv,
                        unsigned* agghu, int n) {
    int t = threadIdx.x;
    int g = blockIdx.x * 16 + (t >> 4);
    int l = t & 15;
    if (g >= n) return;
    unsigned w = p2u[(size_t)g * 16 + l];  // self loop (pads zero)
    double a0 = (double)bf2f((unsigned short)(w & 0xFFFFu));
    double a1 = (double)bf2f((unsigned short)(w >> 16));
    int s = indptr[g], e = indptr[g + 1];
    int i = s;
    for (; i + 7 < e; i += 8) {
        int u0 = csr[i], u1 = csr[i + 1], u2 = csr[i + 2], u3 = csr[i + 3];
        int u4 = csr[i + 4], u5 = csr[i + 5], u6 = csr[i + 6], u7 = csr[i + 7];
        unsigned w0 = p2u[(size_t)u0 * 16 + l];
        unsigned w1 = p2u[(size_t)u1 * 16 + l];
        unsigned w2 = p2u[(size_t)u2 * 16 + l];
        unsigned w3 = p2u[(size_t)u3 * 16 + l];
        unsigned w4 = p2u[(size_t)u4 * 16 + l];
        unsigned w5 = p2u[(size_t)u5 * 16 + l];
        unsigned w6 = p2u[(size_t)u6 * 16 + l];
        unsigned w7 = p2u[(size_t)u7 * 16 + l];
        float f0 = bf2f((unsigned short)(w0 & 0xFFFFu)), g0 = bf2f((unsigned short)(w0 >> 16));
        float f1 = bf2f((unsigned short)(w1 & 0xFFFFu)), g1 = bf2f((unsigned short)(w1 >> 16));
        float f2 = bf2f((unsigned short)(w2 & 0xFFFFu)), g2 = bf2f((unsigned short)(w2 >> 16));
        float f3 = bf2f((unsigned short)(w3 & 0xFFFFu)), g3 = bf2f((unsigned short)(w3 >> 16));
        float f4 = bf2f((unsigned short)(w4 & 0xFFFFu)), g4 = bf2f((unsigned short)(w4 >> 16));
        float f5 = bf2f((unsigned short)(w5 & 0xFFFFu)), g5 = bf2f((unsigned short)(w5 >> 16));
        float f6 = bf2f((unsigned short)(w6 & 0xFFFFu)), g6 = bf2f((unsigned short)(w6 >> 16));
        float f7 = bf2f((unsigned short)(w7 & 0xFFFFu)), g7 = bf2f((unsigned short)(w7 >> 16));
        a0 += ((double)f0 + f1) + ((double)f2 + f3) + ((double)f4 + f5) + ((double)f6 + f7);
        a1 += ((double)g0 + g1) + ((double)g2 + g3) + ((double)g4 + g5) + ((double)g6 + g7);
    }
    for (; i < e; i++) {
        unsigned wv = p2u[(size_t)csr[i] * 16 + l];
        a0 += (double)bf2f((unsigned short)(wv & 0xFFFFu));
        a1 += (double)bf2f((unsigned short)(wv >> 16));
    }
    double r = (double)dinv[g];
    unsigned short o0 = f2bf((float)(a0 * r));
    unsigned short o1 = f2bf((float)(a1 * r));
    agghu[(size_t)g * 16 + l] = (unsigned)o0 | ((unsigned)o1 << 16);  // pads stay 0
}

// h2 = relu((Ah1)W2[:30] + (Ax)W2[30:] + b2); p3 = ([h2,x]@W3) * dinv.
// Block stages its 256 bf16 aggh rows through LDS (stride-17 uints).
__global__ void k_layer2(const unsigned short* aggh, const float2* aggx,
                         const float* x, const float* W2, const float* W3,
                         const float* b2, const float* dinv, float* p3, int n) {
    __shared__ float W2s[32 * 30];
    __shared__ float W3s[32];
    __shared__ float b2s[30];
    __shared__ unsigned hsh[256 * 17];
    int t = threadIdx.x;
    for (int i = t; i < 960; i += 256) W2s[i] = W2[i];
    if (t < 32) W3s[t] = W3[t];
    if (t < 30) b2s[t] = b2[t];
    const unsigned* ag = (const unsigned*)aggh + (size_t)blockIdx.x * 256 * 16;
    int rows = min(256, n - blockIdx.x * 256);
    for (int i = t; i < rows * 16; i += 256) {
        int rr = i >> 4, cc = i & 15;
        hsh[rr * 17 + cc] = ag[i];
    }
    __syncthreads();
    int v = blockIdx.x * 256 + t;
    if (v >= n) return;
    float2 a = aggx[v];
    float acc[30];
#pragma unroll
    for (int j = 0; j < 30; j++)
        acc[j] = fmaf(a.x, W2s[30 * 30 + j], fmaf(a.y, W2s[31 * 30 + j], b2s[j]));
#pragma unroll
    for (int kk = 0; kk < 15; kk++) {  // 30 values = 15 uint pairs
        unsigned pr = hsh[t * 17 + kk];
        float h0 = bf2f((unsigned short)(pr & 0xFFFFu));
        float h1v = bf2f((unsigned short)(pr >> 16));
#pragma unroll
        for (int j = 0; j < 30; j++)
            acc[j] = fmaf(h0, W2s[(2 * kk) * 30 + j], acc[j]);
#pragma unroll
        for (int j = 0; j < 30; j++)
            acc[j] = fmaf(h1v, W2s[(2 * kk + 1) * 30 + j], acc[j]);
    }
    float s3 = 0.f;
#pragma unroll
    for (int j = 0; j < 30; j++) s3 = fmaf(fmaxf(acc[j], 0.f), W3s[j], s3);
    s3 = fmaf(x[2 * v], W3s[30], s3);
    s3 = fmaf(x[2 * v + 1], W3s[31], s3);
    p3[v] = s3 * dinv[v];
}

// out_v = dinv_v * (p3_v + sum p3_u) + b3   (dim 1, x8 unroll, fp64 acc)
__global__ void k_agg1(const float* p3, const int* indptr, const int* csr,
                       const float* dinv, const float* b3, float* out, int n) {
    int v = blockIdx.x * 256 + threadIdx.x;
    if (v >= n) return;
    double acc = (double)p3[v];
    int s = indptr[v], e = indptr[v + 1];
    int i = s;
    for (; i + 7 < e; i += 8) {
        int u0 = csr[i], u1 = csr[i + 1], u2 = csr[i + 2], u3 = csr[i + 3];
        int u4 = csr[i + 4], u5 = csr[i + 5], u6 = csr[i + 6], u7 = csr[i + 7];
        float f0 = p3[u0], f1 = p3[u1], f2 = p3[u2], f3 = p3[u3];
        float f4 = p3[u4], f5 = p3[u5], f6 = p3[u6], f7 = p3[u7];
        acc += ((double)f0 + f1) + ((double)f2 + f3) +
               ((double)f4 + f5) + ((double)f6 + f7);
    }
    for (; i < e; i++) acc += (double)p3[csr[i]];
    out[v] = (float)(acc * (double)dinv[v] + (double)b3[0]);
}

extern "C" void kernel_launch(void* const* d_in, const int* in_sizes, int n_in,
                              void* d_out, int out_size, void* d_ws, size_t ws_size,
                              hipStream_t stream) {
    const float* x  = (const float*)d_in[0];
    const void*  ei = d_in[1];
    const float* W1 = (const float*)d_in[2];
    const float* b1 = (const float*)d_in[3];
    const float* W2 = (const float*)d_in[4];
    const float* b2 = (const float*)d_in[5];
    const float* W3 = (const float*)d_in[6];
    const float* b3 = (const float*)d_in[7];
    float* out = (float*)d_out;
    const int n = in_sizes[0] / 2;
    const long long E = in_sizes[1] / 2;
    const int B = (n + 255) / 256;  // dst buckets of 256 nodes

    char* w = (char*)d_ws;
    auto alloc = [&](size_t b) { void* p = (void*)w; w += (b + 255) & ~(size_t)255; return p; };
    int*            block_cnt   = (int*)alloc((size_t)B * NBB * 4);
    int*            bucket_cnt  = (int*)alloc((size_t)B * 4);
    int*            bucket_base = (int*)alloc(((size_t)B + 1) * 4);
    unsigned*       binned      = (unsigned*)alloc((size_t)E * 4);
    int*            indptr      = (int*)alloc(((size_t)n + 1) * 4);
    float*          dinv        = (float*)alloc((size_t)n * 4);
    int*            csr         = (int*)alloc((size_t)E * 4);
    float2*         p1          = (float2*)alloc((size_t)n * 8);
    float2*         aggx        = (float2*)alloc((size_t)n * 8);
    unsigned short* p2          = (unsigned short*)alloc((size_t)n * 32 * 2);
    unsigned short* aggh        = (unsigned short*)alloc((size_t)n * 32 * 2);
    float*          p3          = (float*)alloc((size_t)n * 4);

    int nblocks = (n + 255) / 256;
    size_t lds = (size_t)B * 4;

    k_binA<<<NBB, 256, lds, stream>>>(ei, E, block_cnt, B);
    k_colsum<<<B, 256, 0, stream>>>(block_cnt, bucket_cnt);
    k_bucketscan<<<1, 256, 0, stream>>>(bucket_cnt, bucket_base, B, E, indptr, n);
    k_binB<<<NBB, 256, lds, stream>>>(ei, E, block_cnt, bucket_base, binned, B);
    k_bucket_csr<<<B, 256, 0, stream>>>(binned, bucket_base, x, indptr, dinv, p1, csr, n);
    k_agg2_l1<<<nblocks, 256, 0, stream>>>(p1, indptr, csr, dinv, W1, b1, aggx, p2, n);
    k_agg30<<<(n + 15) / 16, 256, 0, stream>>>((const unsigned*)p2, indptr, csr, dinv,
                                               (unsigned*)aggh, n);
    k_layer2<<<nblocks, 256, 0, stream>>>(aggh, aggx, x, W2, W3, b2, dinv, p3, n);
    k_agg1<<<nblocks, 256, 0, stream>>>(p3, indptr, csr, dinv, b3, out, n);
}